// Round 5
// baseline (2117.253 us; speedup 1.0000x reference)
//
#include <hip/hip_runtime.h>
#include <math.h>

// DynamiSE: GCN + 2x RK4 neural ODE + combine/LN.
// R1: CSR gather, coef folded into matmul (hs = dinv * x@W).
// R2: mm32 fused into agg epilogue, hs double-buffered.
// R3: merged pos/neg dispatch.
// R4: fp16 hs (64B gather rows). FAILED replay (read-before-write of poison).
// R5: blanket memset(0) of used ws every call (determinism insurance).
// R6: radix CSR build REGRESSED (bucket windows thrash all 8 L2s) -> reverted.
// R7: persistent kernel REGRESSED (gather is fabric-fetch-bound) -> reverted.
// R9: XCD-split + fp16 ksum: small gain; gather fabric replication is structural.
// R10: rank-based atomic-free CSR fill (rank recorded in count pass).
// R11: XCD-local (workgroup-scope) atomics: NEUTRAL. ~23G op/s memory-side
//      atomic wall regardless of scope. count is a HW wall.
// R12: count+mm fusion (mm hidden under atomic wall); narrow memset; u16 rank.
// R13: f32-temp + fill-fused scale; stage0 dual-mm epilogue; stage4+combine/LN
//      fused; scan_sums absorbed. 2023->1954us.
// R14: pipelined CSR build: count ALL first (wall 200->141us), pn count hidden
//      under ALL-fill, pn fill hidden under stage0. 1954->1908us. Validated.
// R15: nt (non-temporal) hints on ALL single-use-per-dispatch linear streams
//      (x, ksum, csr, rank, temp, edge lists, H_t, out). Rationale: each agg
//      dispatch streams ~45MB linear through the 4MB/XCD L2s that need to
//      keep the 6.4MB hs gather set resident; nt = no-allocate/evict-first
//      stops the pollution. hs gather path stays cached. Memset: cnt3 only
//      on rank path (cur3 unused there).

#define TPB 256
#define SCAN_T 1024

typedef _Float16 h8 __attribute__((ext_vector_type(8)));
typedef float f8 __attribute__((ext_vector_type(8)));

template <typename T>
__device__ __forceinline__ T ntl(const T* p) { return __builtin_nontemporal_load(p); }
template <typename T>
__device__ __forceinline__ void nts(T* p, T v) { __builtin_nontemporal_store(v, p); }

// ---------- CSR build ----------

struct SegG { const int* src; const int* dst; int n; int goff; };
struct FSeg { const int* src; const int* dst; int n; const int* offs; int* cur; };

// count ALL graph (2 segs, goff=0) + mm128 (temp = H_t @ W_init, f32).
__global__ __launch_bounds__(TPB) void count_mm_all(
        SegG s0, SegG s1, int* __restrict__ cnt3,
        unsigned short* __restrict__ rank,
        const float* __restrict__ x, const float* __restrict__ W,
        float* __restrict__ temp, int N, int cntB, int mmB) {
    __shared__ float Ws[128][32];
    __shared__ float xs[8][128];

    int g2 = blockIdx.x >> 1, r2 = blockIdx.x & 1;
    if (r2 == 0) {
        int cb = g2;
        if (cb >= cntB) return;
        int i = cb * TPB + threadIdx.x;
        SegG s; int e;
        if (i < s0.n) { s = s0; e = i; }
        else if (i < s0.n + s1.n) { s = s1; e = i - s0.n; }
        else return;
        int d = ntl(&s.dst[e]);
        int sr = ntl(&s.src[e]);
        int r = atomicAdd(&cnt3[d], 1);
        if (rank) nts(&rank[i], (unsigned short)r);
        (void)sr;
        // note: src not needed here, but keeping load out (compiler drops it)
    } else {
        int mb = g2;
        if (mb >= mmB) return;
        int tid = threadIdx.x;
        for (int i = tid; i < 128 * 32; i += TPB) Ws[i >> 5][i & 31] = W[i];
        int base = mb * 8;
        for (int i = tid; i < 8 * 128; i += TPB) {
            int idx = base * 128 + i;
            xs[i >> 7][i & 127] = (idx < N * 128) ? ntl(&x[idx]) : 0.0f;
        }
        __syncthreads();
        int row = tid >> 5, c = tid & 31;
        int gr = base + row;
        float acc = 0.0f;
#pragma unroll
        for (int k = 0; k < 128; ++k) acc += xs[row][k] * Ws[k][c];
        if (gr < N) nts(&temp[gr * 32 + c], acc);
    }
}

// fallback: 4-seg count + mm (rank optional)
__global__ __launch_bounds__(TPB) void count_mm(
        SegG s0, SegG s1, SegG s2, SegG s3, int* __restrict__ cnt3,
        unsigned short* __restrict__ rank,
        const float* __restrict__ x, const float* __restrict__ W,
        float* __restrict__ temp, int N, int cntB, int mmB) {
    __shared__ float Ws[128][32];
    __shared__ float xs[8][128];

    int g5 = blockIdx.x / 5, r5 = blockIdx.x % 5;
    if (r5 < 3) {
        int cb = g5 * 3 + r5;
        if (cb >= cntB) return;
        int i = cb * TPB + threadIdx.x;
        SegG s; int e;
        if (i < s0.n) { s = s0; e = i; }
        else if (i < s0.n + s1.n) { s = s1; e = i - s0.n; }
        else if (i < s0.n + s1.n + s2.n) { s = s2; e = i - s0.n - s1.n; }
        else if (i < s0.n + s1.n + s2.n + s3.n) { s = s3; e = i - s0.n - s1.n - s2.n; }
        else return;
        int r = atomicAdd(&cnt3[s.goff + s.dst[e]], 1);
        if (rank) rank[i] = (unsigned short)r;
    } else {
        int mb = g5 * 2 + (r5 - 3);
        if (mb >= mmB) return;
        int tid = threadIdx.x;
        for (int i = tid; i < 128 * 32; i += TPB) Ws[i >> 5][i & 31] = W[i];
        int base = mb * 8;
        for (int i = tid; i < 8 * 128; i += TPB) {
            int idx = base * 128 + i;
            xs[i >> 7][i & 127] = (idx < N * 128) ? x[idx] : 0.0f;
        }
        __syncthreads();
        int row = tid >> 5, c = tid & 31;
        int gr = base + row;
        float acc = 0.0f;
#pragma unroll
        for (int k = 0; k < 128; ++k) acc += xs[row][k] * Ws[k][c];
        if (gr < N) temp[gr * 32 + c] = acc;
    }
}

// fill ALL csr (atomic-free) + hs scale + count pos/neg (atomics), 8:1:4.
__global__ __launch_bounds__(TPB) void fill_scale_count(
        SegG a0, SegG a1, SegG p2, SegG p3,
        const int* __restrict__ offs3, unsigned short* __restrict__ rank,
        int* __restrict__ csr,
        const float* __restrict__ temp, const float* __restrict__ dinv,
        _Float16* __restrict__ hs, int* __restrict__ cnt3,
        int N, int Eall, int fillB, int scaleB, int cntB) {
    int g = blockIdx.x / 13, r = blockIdx.x % 13;
    if (r < 8) {
        int fb = g * 8 + r;
        if (fb >= fillB) return;
        int i = fb * TPB + threadIdx.x;
        SegG s; int e;
        if (i < a0.n) { s = a0; e = i; }
        else if (i < a0.n + a1.n) { s = a1; e = i - a0.n; }
        else return;
        int d = ntl(&s.dst[e]);
        int sr = ntl(&s.src[e]);
        int rk = (int)ntl(&rank[i]);
        nts(&csr[offs3[d] + rk], sr);
    } else if (r == 8) {
        int c = g * TPB + threadIdx.x;
        if (c < N * 4) {
            f8 v = ntl(&((const f8*)temp)[c]);
            ((h8*)hs)[c] = __builtin_convertvector(v * dinv[c >> 2], h8);
        }
    } else {
        int cb = g * 4 + (r - 9);
        if (cb >= cntB) return;
        int j = cb * TPB + threadIdx.x;
        SegG s; int e;
        if (j < p2.n) { s = p2; e = j; }
        else if (j < p2.n + p3.n) { s = p3; e = j - p2.n; }
        else return;
        int d = ntl(&s.dst[e]);
        int rr = atomicAdd(&cnt3[s.goff + d], 1);
        nts(&rank[Eall + j], (unsigned short)rr);
    }
}

// standalone scale (fallback path only)
__global__ void scale_hs(const float* __restrict__ temp, const float* __restrict__ dinv,
                         _Float16* __restrict__ hs, int N) {
    int c = blockIdx.x * blockDim.x + threadIdx.x;
    if (c < N * 4) {
        f8 v = ((const f8*)temp)[c];
        ((h8*)hs)[c] = __builtin_convertvector(v * dinv[c >> 2], h8);
    }
}

// fallback cursor fill (4 segs)
__global__ void fill4(FSeg s0, FSeg s1, FSeg s2, FSeg s3, int* __restrict__ csr) {
    int i = blockIdx.x * blockDim.x + threadIdx.x;
    FSeg s; int e;
    if (i < s0.n) { s = s0; e = i; }
    else if (i < s0.n + s1.n) { s = s1; e = i - s0.n; }
    else if (i < s0.n + s1.n + s2.n) { s = s2; e = i - s0.n - s1.n; }
    else if (i < s0.n + s1.n + s2.n + s3.n) { s = s3; e = i - s0.n - s1.n - s2.n; }
    else return;
    int d = s.dst[e];
    int pos = s.offs[d] + atomicAdd(&s.cur[d], 1);
    csr[pos] = s.src[e];
}

// scan over counts; also emits dinv
__global__ void scan_block(const int* __restrict__ in, int n, int* __restrict__ out,
                           int* __restrict__ bsums, float* __restrict__ dinv) {
    __shared__ int sh[SCAN_T];
    int tx = threadIdx.x;
    int g = blockIdx.x * SCAN_T + tx;
    int v = (g < n) ? in[g] : 0;
    if (g < n) dinv[g] = rsqrtf(1.0f + (float)v);
    sh[tx] = v;
    __syncthreads();
    for (int off = 1; off < SCAN_T; off <<= 1) {
        int t = (tx >= off) ? sh[tx - off] : 0;
        __syncthreads();
        sh[tx] += t;
        __syncthreads();
    }
    if (g < n) out[g] = sh[tx] - v;
    if (tx == SCAN_T - 1) bsums[blockIdx.x] = sh[tx];
}

__global__ void scan_sums(int* __restrict__ bsums, int nb) {
    __shared__ int sh[SCAN_T];
    int tx = threadIdx.x;
    int v = (tx < nb) ? bsums[tx] : 0;
    sh[tx] = v;
    __syncthreads();
    for (int off = 1; off < SCAN_T; off <<= 1) {
        int t = (tx >= off) ? sh[tx - off] : 0;
        __syncthreads();
        sh[tx] += t;
        __syncthreads();
    }
    if (tx < nb) bsums[tx] = sh[tx] - v;
}

__global__ void scan_add(int* __restrict__ offs, const int* __restrict__ bsums, int n,
                         int total, int base) {
    int g = blockIdx.x * blockDim.x + threadIdx.x;
    if (g < n) offs[g] += bsums[g >> 10] + base;
    if (g == 0) offs[n] = base + total;
}

// scan_add with scan_sums absorbed (raw bsums; LDS prefix). nbs <= 1024.
__global__ void scan_add2(int* __restrict__ offs, const int* __restrict__ bsums,
                          int n, int total, int nbs, int base) {
    __shared__ int sb[SCAN_T];
    int tid = threadIdx.x;
    for (int i = tid; i < nbs; i += TPB) sb[i] = bsums[i];
    __syncthreads();
    int g = blockIdx.x * TPB + tid;
    if (g < n) {
        int b = g >> 10;
        int pre = 0;
        for (int j = 0; j < b; ++j) pre += sb[j];
        offs[g] += pre + base;
    }
    if (g == 0) offs[n] = base + total;
}

// ---------- seed matmul (fallback path only) ----------

__global__ void mm32_kernel(const float* __restrict__ x, const float* __restrict__ W,
                            const float* __restrict__ dinv, _Float16* __restrict__ hs, int N) {
    __shared__ float Ws[32][32];
    __shared__ float xs[8][32];
    int tid = threadIdx.x;
    for (int i = tid; i < 32 * 32; i += TPB) Ws[i >> 5][i & 31] = W[i];
    int base = blockIdx.x * 8;
    {
        int idx = base * 32 + tid;
        xs[tid >> 5][tid & 31] = (idx < N * 32) ? x[idx] : 0.0f;
    }
    __syncthreads();
    int row = tid >> 5, c = tid & 31;
    int gr = base + row;
    float acc = 0.0f;
#pragma unroll
    for (int k = 0; k < 32; ++k) acc += xs[row][k] * Ws[k][c];
    if (gr < N) hs[gr * 32 + c] = (_Float16)(acc * dinv[gr]);
}

// ---------- fused CSR aggregate + RK4 stage + next matmul ----------

struct Job {
    const int* offs; const int* csr;
    const _Float16* hs_in; _Float16* hs_out;
    const float* dinv; const float* dinv_next;
    const float* bias; const float* wt;
    _Float16* ksum; float* x;
    const float* W;
    const float* W2; const float* dinv2; _Float16* hs_out2;  // stage0 only
};

// stage0 (all-graph gather + relu + dual mm epilogue) fused with pos/neg fill.
__global__ __launch_bounds__(TPB) void stage0_fill(
        Job J, SegG p2, SegG p3,
        const int* __restrict__ offs3, const unsigned short* __restrict__ rank,
        int* __restrict__ csr, int Eall,
        float* __restrict__ x2, int N, int nbg, int fillB) {
    __shared__ float Ws[32][32];
    __shared__ float Ws2[32][32];
    __shared__ float xts[64][36];
    __shared__ int soffs[65];

    int g = blockIdx.x / 5, r = blockIdx.x % 5;
    if (r != 0) {
        int fb = g * 4 + (r - 1);
        if (fb >= fillB) return;
        int j = fb * TPB + threadIdx.x;
        SegG s; int e;
        if (j < p2.n) { s = p2; e = j; }
        else if (j < p2.n + p3.n) { s = p3; e = j - p2.n; }
        else return;
        int d = ntl(&s.dst[e]);
        int sr = ntl(&s.src[e]);
        int rk = (int)ntl(&rank[Eall + j]);
        nts(&csr[offs3[s.goff + d] + rk], sr);
        return;
    }
    int bid = g;
    if (bid >= nbg) return;

    int nbase = bid * 64;
    int tid = threadIdx.x;
    int lnode = tid >> 2, q = tid & 3;
    int node = nbase + lnode;
    bool valid = node < N;

    for (int i = tid; i < 32 * 32; i += TPB) Ws[i >> 5][i & 31] = J.W[i];
    if (J.W2) {
        for (int i = tid; i < 32 * 32; i += TPB) Ws2[i >> 5][i & 31] = J.W2[i];
    }
    if (tid < 65) {
        int ix = nbase + tid; if (ix > N) ix = N;
        soffs[tid] = J.offs[ix];
    }
    __syncthreads();

    f8 xrow;
#pragma unroll
    for (int j = 0; j < 8; ++j) xrow[j] = 0.f;

    if (valid) {
        const h8* hsv = (const h8*)J.hs_in;
        const int* __restrict__ csre = J.csr;
        int r0 = soffs[lnode], r1 = soffs[lnode + 1];
        f8 acc = __builtin_convertvector(hsv[node * 4 + q], f8); // self-loop
        int i = r0;
        for (; i + 4 <= r1; i += 4) {
            int e0 = ntl(&csre[i]), e1 = ntl(&csre[i + 1]);
            int e2 = ntl(&csre[i + 2]), e3 = ntl(&csre[i + 3]);
            h8 v0 = hsv[e0 * 4 + q];
            h8 v1 = hsv[e1 * 4 + q];
            h8 v2 = hsv[e2 * 4 + q];
            h8 v3 = hsv[e3 * 4 + q];
            acc += (__builtin_convertvector(v0, f8) + __builtin_convertvector(v1, f8))
                 + (__builtin_convertvector(v2, f8) + __builtin_convertvector(v3, f8));
        }
        for (; i < r1; ++i)
            acc += __builtin_convertvector(hsv[ntl(&csre[i]) * 4 + q], f8);

        float dv = J.dinv[node];
        f8 bb = ((const f8*)J.bias)[q];
        f8 kv;
#pragma unroll
        for (int j = 0; j < 8; ++j) kv[j] = fmaxf(acc[j] * dv + bb[j], 0.f);
        int idx = node * 4 + q;
        nts(&((f8*)J.x)[idx], kv);
        nts(&((f8*)x2)[idx], kv);
        xrow = kv;
#pragma unroll
        for (int j = 0; j < 8; ++j) xts[lnode][q * 8 + j] = xrow[j];
    }
    __syncthreads();
    if (valid) {
        f8 accm;
#pragma unroll
        for (int j = 0; j < 8; ++j) accm[j] = 0.f;
#pragma unroll
        for (int k = 0; k < 32; ++k) {
            float xv = xts[lnode][k];
            f8 w = *(const f8*)&Ws[k][q * 8];
            accm += xv * w;
        }
        accm *= J.dinv_next[node];
        ((h8*)J.hs_out)[node * 4 + q] = __builtin_convertvector(accm, h8);
        if (J.W2) {
            f8 acc2;
#pragma unroll
            for (int j = 0; j < 8; ++j) acc2[j] = 0.f;
#pragma unroll
            for (int k = 0; k < 32; ++k) {
                float xv = xts[lnode][k];
                f8 w = *(const f8*)&Ws2[k][q * 8];
                acc2 += xv * w;
            }
            acc2 *= J.dinv2[node];
            ((h8*)J.hs_out2)[node * 4 + q] = __builtin_convertvector(acc2, h8);
        }
    }
}

// RK4 stages 1-4 (+ next matmul). 4 lanes/node, 64 nodes/block.
// R15: nt on all single-use linear streams (csr, x, ksum); hs gather cached.
__global__ __launch_bounds__(TPB) void agg_stage(Job jp, Job jn, int nbg, float t,
                                                 int stage, int do_mm, int split, int N) {
    __shared__ float Ws[32][32];
    __shared__ float xts[64][36];
    __shared__ int soffs[65];

    bool isP; int bid;
    if (split) {
        int xcd = blockIdx.x & 7;
        isP = xcd < 4;
        bid = ((int)blockIdx.x >> 3) * 4 + (xcd & 3);
        if (bid >= nbg) return;
    } else {
        isP = (int)blockIdx.x < nbg;
        bid = isP ? blockIdx.x : (blockIdx.x - nbg);
    }
    const Job& J = isP ? jp : jn;
    int nbase = bid * 64;
    int tid = threadIdx.x;
    int lnode = tid >> 2, q = tid & 3;
    int node = nbase + lnode;
    bool valid = node < N;

    if (do_mm) {
        for (int i = tid; i < 32 * 32; i += TPB) Ws[i >> 5][i & 31] = J.W[i];
    }
    if (tid < 65) {
        int ix = nbase + tid; if (ix > N) ix = N;
        soffs[tid] = J.offs[ix];
    }
    __syncthreads();

    f8 xrow;
#pragma unroll
    for (int j = 0; j < 8; ++j) xrow[j] = 0.f;

    if (valid) {
        const h8* hsv = (const h8*)J.hs_in;
        const int* __restrict__ csr = J.csr;
        int r0 = soffs[lnode], r1 = soffs[lnode + 1];
        f8 acc = __builtin_convertvector(hsv[node * 4 + q], f8); // self-loop
        int i = r0;
        for (; i + 4 <= r1; i += 4) {
            int e0 = ntl(&csr[i]), e1 = ntl(&csr[i + 1]);
            int e2 = ntl(&csr[i + 2]), e3 = ntl(&csr[i + 3]);
            h8 v0 = hsv[e0 * 4 + q];
            h8 v1 = hsv[e1 * 4 + q];
            h8 v2 = hsv[e2 * 4 + q];
            h8 v3 = hsv[e3 * 4 + q];
            acc += (__builtin_convertvector(v0, f8) + __builtin_convertvector(v1, f8))
                 + (__builtin_convertvector(v2, f8) + __builtin_convertvector(v3, f8));
        }
        for (; i < r1; ++i)
            acc += __builtin_convertvector(hsv[ntl(&csr[i]) * 4 + q], f8);

        float dv = J.dinv[node];
        f8 bb = ((const f8*)J.bias)[q];
        f8 kv;
#pragma unroll
        for (int j = 0; j < 8; ++j) kv[j] = fmaxf(acc[j] * dv + bb[j], 0.f);
        f8 w = ((const f8*)J.wt)[q];
#pragma unroll
        for (int j = 0; j < 8; ++j) kv[j] *= 1.f / (1.f + expf(-t * w[j]));

        int idx = node * 4 + q;
        f8* x8 = (f8*)J.x;
        h8* ks8 = (h8*)J.ksum;
        if (stage == 4) {
            f8 ks = __builtin_convertvector(ntl(&ks8[idx]), f8);
            f8 xv = ntl(&x8[idx]);
            const float cc = 0.1f / 6.0f;
#pragma unroll
            for (int j = 0; j < 8; ++j) xv[j] += cc * (ks[j] + kv[j]);
            nts(&x8[idx], xv);
            xrow = xv;
        } else {
            float a = (stage == 3) ? 0.1f : 0.05f;
            f8 xv = ntl(&x8[idx]);
#pragma unroll
            for (int j = 0; j < 8; ++j) xrow[j] = xv[j] + a * kv[j];
            if (stage == 1) {
                nts(&ks8[idx], __builtin_convertvector(kv, h8));
            } else {
                f8 ks = __builtin_convertvector(ntl(&ks8[idx]), f8);
#pragma unroll
                for (int j = 0; j < 8; ++j) ks[j] += 2.f * kv[j];
                nts(&ks8[idx], __builtin_convertvector(ks, h8));
            }
        }
    }

    if (do_mm) {
        if (valid) {
#pragma unroll
            for (int j = 0; j < 8; ++j) xts[lnode][q * 8 + j] = xrow[j];
        }
        __syncthreads();
        if (valid) {
            f8 accm;
#pragma unroll
            for (int j = 0; j < 8; ++j) accm[j] = 0.f;
#pragma unroll
            for (int k = 0; k < 32; ++k) {
                float xv = xts[lnode][k];
                f8 w = *(const f8*)&Ws[k][q * 8];
                accm += xv * w;
            }
            accm *= J.dinv_next[node];
            ((h8*)J.hs_out)[node * 4 + q] = __builtin_convertvector(accm, h8);
        }
    }
}

// ---------- final RK4 stage fused with combine + layernorm ----------
__global__ __launch_bounds__(TPB) void stage4_combine(
        Job jp, Job jn, float t,
        const float* __restrict__ Wc, const float* __restrict__ bc,
        const float* __restrict__ lg, const float* __restrict__ lb,
        float* __restrict__ out, int N) {
    __shared__ float Ws[64][32];
    __shared__ float xts[64][68];
    __shared__ int soffs[65];

    int tid = threadIdx.x;
    for (int i = tid; i < 64 * 32; i += TPB) Ws[i >> 5][i & 31] = Wc[i];
    int nbase = blockIdx.x * 64;
    int lnode = tid >> 2, q = tid & 3;
    int node = nbase + lnode;
    bool valid = node < N;

    for (int side = 0; side < 2; ++side) {
        const Job& J = side ? jn : jp;
        __syncthreads();
        if (tid < 65) {
            int ix = nbase + tid; if (ix > N) ix = N;
            soffs[tid] = J.offs[ix];
        }
        __syncthreads();
        if (valid) {
            const h8* hsv = (const h8*)J.hs_in;
            const int* __restrict__ csr = J.csr;
            int r0 = soffs[lnode], r1 = soffs[lnode + 1];
            f8 acc = __builtin_convertvector(hsv[node * 4 + q], f8);
            int i = r0;
            for (; i + 4 <= r1; i += 4) {
                int e0 = ntl(&csr[i]), e1 = ntl(&csr[i + 1]);
                int e2 = ntl(&csr[i + 2]), e3 = ntl(&csr[i + 3]);
                h8 v0 = hsv[e0 * 4 + q];
                h8 v1 = hsv[e1 * 4 + q];
                h8 v2 = hsv[e2 * 4 + q];
                h8 v3 = hsv[e3 * 4 + q];
                acc += (__builtin_convertvector(v0, f8) + __builtin_convertvector(v1, f8))
                     + (__builtin_convertvector(v2, f8) + __builtin_convertvector(v3, f8));
            }
            for (; i < r1; ++i)
                acc += __builtin_convertvector(hsv[ntl(&csr[i]) * 4 + q], f8);

            float dv = J.dinv[node];
            f8 bb = ((const f8*)J.bias)[q];
            f8 kv;
#pragma unroll
            for (int j = 0; j < 8; ++j) kv[j] = fmaxf(acc[j] * dv + bb[j], 0.f);
            f8 w = ((const f8*)J.wt)[q];
#pragma unroll
            for (int j = 0; j < 8; ++j) kv[j] *= 1.f / (1.f + expf(-t * w[j]));

            int idx = node * 4 + q;
            f8 ks = __builtin_convertvector(ntl(&((const h8*)J.ksum)[idx]), f8);
            f8 xv = ntl(&((const f8*)J.x)[idx]);
            const float cc = 0.1f / 6.0f;
#pragma unroll
            for (int j = 0; j < 8; ++j)
                xts[lnode][side * 32 + q * 8 + j] = xv[j] + cc * (ks[j] + kv[j]);
        }
    }
    __syncthreads();

    if (valid) {
        f8 bcv = ((const f8*)bc)[q];
        f8 accm;
#pragma unroll
        for (int j = 0; j < 8; ++j) accm[j] = bcv[j];
#pragma unroll
        for (int k = 0; k < 64; ++k) {
            float xv = xts[lnode][k];
            f8 w = *(const f8*)&Ws[k][q * 8];
            accm += xv * w;
        }
        float s = 0.f, sq = 0.f;
#pragma unroll
        for (int j = 0; j < 8; ++j) { s += accm[j]; sq += accm[j] * accm[j]; }
        s += __shfl_xor(s, 1); s += __shfl_xor(s, 2);
        sq += __shfl_xor(sq, 1); sq += __shfl_xor(sq, 2);
        float mu = s * (1.0f / 32.0f);
        float var = sq * (1.0f / 32.0f) - mu * mu;
        float rs = rsqrtf(var + 1e-5f);
        f8 gv = ((const f8*)lg)[q];
        f8 bv = ((const f8*)lb)[q];
        f8 o;
#pragma unroll
        for (int j = 0; j < 8; ++j) o[j] = (accm[j] - mu) * rs * gv[j] + bv[j];
        nts(&((f8*)out)[node * 4 + q], o);
    }
}

// ---------- combine + layernorm (fallback path only) ----------

__global__ void combine_kernel(const float* __restrict__ zp, const float* __restrict__ zn,
                               const float* __restrict__ Wc, const float* __restrict__ bc,
                               const float* __restrict__ g, const float* __restrict__ be,
                               float* __restrict__ out, int N) {
    __shared__ float Ws[64][32];
    __shared__ float zs[8][64];
    int tid = threadIdx.x;
    for (int i = tid; i < 64 * 32; i += TPB) Ws[i >> 5][i & 31] = Wc[i];
    int base = blockIdx.x * 8;
    {
        int r = tid >> 5, c = tid & 31;
        int gr = base + r;
        zs[r][c] = (gr < N) ? zp[gr * 32 + c] : 0.0f;
        zs[r][32 + c] = (gr < N) ? zn[gr * 32 + c] : 0.0f;
    }
    __syncthreads();
    int row = tid >> 5, c = tid & 31;
    int gr = base + row;
    float acc = bc[c];
#pragma unroll
    for (int k = 0; k < 64; ++k) acc += zs[row][k] * Ws[k][c];
    float s = acc, sq = acc * acc;
#pragma unroll
    for (int off = 16; off; off >>= 1) {
        s += __shfl_xor(s, off, 32);
        sq += __shfl_xor(sq, off, 32);
    }
    float mu = s * (1.0f / 32.0f);
    float var = sq * (1.0f / 32.0f) - mu * mu;
    float y = (acc - mu) * rsqrtf(var + 1e-5f) * g[c] + be[c];
    if (gr < N) out[gr * 32 + c] = y;
}

// ---------- host orchestration ----------

extern "C" void kernel_launch(void* const* d_in, const int* in_sizes, int n_in,
                              void* d_out, int out_size, void* d_ws, size_t ws_size,
                              hipStream_t stream) {
    const float* H_t = (const float*)d_in[0];
    const int* Apos = (const int*)d_in[1];
    const int* Aneg = (const int*)d_in[2];
    const int* dApos = (const int*)d_in[3];
    const int* dAneg = (const int*)d_in[4];
    const float* W_init = (const float*)d_in[5];
    const float* b_init = (const float*)d_in[6];
    const float* W_pos = (const float*)d_in[7];
    const float* b_pos = (const float*)d_in[8];
    const float* wt_pos = (const float*)d_in[9];
    const float* W_neg = (const float*)d_in[10];
    const float* b_neg = (const float*)d_in[11];
    const float* wt_neg = (const float*)d_in[12];
    const float* W_comb = (const float*)d_in[13];
    const float* b_comb = (const float*)d_in[14];
    const float* ln_g = (const float*)d_in[15];
    const float* ln_b = (const float*)d_in[16];

    const int N = in_sizes[0] / 128;
    const int E1 = in_sizes[1] / 2;
    const int E2 = in_sizes[2] / 2;
    const int DE1 = in_sizes[3] / 2;
    const int DE2 = in_sizes[4] / 2;
    const int Eall = E1 + E2;
    const int Epn = DE1 + DE2;
    const int Etot = Eall + Epn;
    const int n3 = 3 * N;

    const int* Apos_src = Apos, * Apos_dst = Apos + E1;
    const int* Aneg_src = Aneg, * Aneg_dst = Aneg + E2;
    const int* dApos_src = dApos, * dApos_dst = dApos + DE1;
    const int* dAneg_src = dAneg, * dAneg_dst = dAneg + DE2;

    const size_t n32 = (size_t)N * 32;
    const size_t szf = n32 * 4;
    const size_t szh = n32 * 2;
    auto al = [](size_t b) { return (b + 255) & ~(size_t)255; };

    size_t small_bytes = 3 * al((size_t)n3 * 4)        /* dinv3, cnt3, cur3 */
                       + al(((size_t)n3 + 1) * 4)      /* offs3 */
                       + al((size_t)Etot * 4)          /* csr3 */
                       + al(SCAN_T * 4);
    size_t need_merged = 2 * al(szf) + 6 * al(szh) + small_bytes;
    size_t need_rank = need_merged + al((size_t)Etot * 2);   // u16 rank
    bool merged = ws_size >= need_merged + 4096;
    bool use_rank = ws_size >= need_rank + 4096;

    char* p = (char*)d_ws;
    auto alloc = [&](size_t bytes) -> void* {
        void* r = (void*)p;
        p += al(bytes);
        return r;
    };
    float* x_pos = (float*)alloc(szf);   // also: f32 temp for init mm (pre-stage0)
    float* x_neg = (float*)alloc(szf);
    _Float16* ksum_p = (_Float16*)alloc(szh);
    _Float16* ksum_n = merged ? (_Float16*)alloc(szh) : ksum_p;
    _Float16* hs_pa = (_Float16*)alloc(szh);
    _Float16* hs_pb = (_Float16*)alloc(szh);
    _Float16* hs_na = merged ? (_Float16*)alloc(szh) : hs_pa;
    _Float16* hs_nb = merged ? (_Float16*)alloc(szh) : hs_pb;
    float* dinv3 = (float*)alloc((size_t)n3 * 4);
    int* cnt3 = (int*)alloc((size_t)n3 * 4);
    int* cur3 = (int*)alloc((size_t)n3 * 4);
    int* offs3 = (int*)alloc(((size_t)n3 + 1) * 4);
    int* csr3 = (int*)alloc((size_t)Etot * 4);
    int* bsums = (int*)alloc(SCAN_T * 4);
    unsigned short* rank = use_rank ? (unsigned short*)alloc((size_t)Etot * 2) : nullptr;

    // Narrow memset: cnt3 always; cur3 only needed on the fallback cursor path.
    if (use_rank) {
        hipMemsetAsync(cnt3, 0, al((size_t)n3 * 4), stream);
    } else {
        hipMemsetAsync(cnt3, 0, 2 * al((size_t)n3 * 4), stream);
    }

    float* dinv_all = dinv3, * dinv_pos = dinv3 + N, * dinv_neg = dinv3 + 2 * N;
    const int* offs_all = offs3, * offs_pos = offs3 + N, * offs_neg = offs3 + 2 * N;

    dim3 blk(TPB);
    auto gblk = [](int n) { return dim3((n + TPB - 1) / TPB); };
    dim3 grid_rows((N + 7) / 8);
    const int nb64 = (N + 63) / 64;
    const int nsplit = ((nb64 + 3) / 4) * 8;
    const int mmB = (N + 7) / 8;
    const int scaleB = (N * 4 + TPB - 1) / TPB;

    SegG a0 = { Apos_src, Apos_dst, E1, 0 };
    SegG a1 = { Aneg_src, Aneg_dst, E2, 0 };
    SegG p2 = { dApos_src, dApos_dst, DE1, N };
    SegG p3 = { dAneg_src, dAneg_dst, DE2, 2 * N };

    auto mkjob = [&](const int* offs, const _Float16* hs_in, _Float16* hs_out,
                     const float* dinv, const float* dinv_next, const float* bias,
                     const float* wt, _Float16* ksum, float* x, const float* W) {
        Job j; j.offs = offs; j.csr = csr3; j.hs_in = hs_in; j.hs_out = hs_out;
        j.dinv = dinv; j.dinv_next = dinv_next; j.bias = bias; j.wt = wt;
        j.ksum = ksum; j.x = x; j.W = W;
        j.W2 = nullptr; j.dinv2 = nullptr; j.hs_out2 = nullptr; return j;
    };

    if (use_rank) {
        // ---- pipelined build ----
        const int cntBall = (Eall + TPB - 1) / TPB;
        count_mm_all<<<dim3(2 * max(cntBall, mmB)), blk, 0, stream>>>(
            a0, a1, cnt3, rank, H_t, W_init, x_pos, N, cntBall, mmB);
        const int nbsA = (N + SCAN_T - 1) / SCAN_T;
        scan_block<<<nbsA, SCAN_T, 0, stream>>>(cnt3, N, offs3, bsums, dinv3);
        scan_add2<<<gblk(N), blk, 0, stream>>>(offs3, bsums, N, Eall, nbsA, 0);
        const int cntBpn = (Epn + TPB - 1) / TPB;
        {
            const int g13 = max(max((cntBall + 7) / 8, scaleB), (cntBpn + 3) / 4);
            fill_scale_count<<<dim3(13 * g13), blk, 0, stream>>>(
                a0, a1, p2, p3, offs3, rank, csr3, x_pos, dinv_all, hs_pa,
                cnt3, N, Eall, cntBall, scaleB, cntBpn);
        }
        const int nbsP = (2 * N + SCAN_T - 1) / SCAN_T;
        scan_block<<<nbsP, SCAN_T, 0, stream>>>(cnt3 + N, 2 * N, offs3 + N, bsums, dinv3 + N);
        scan_add2<<<gblk(2 * N), blk, 0, stream>>>(offs3 + N, bsums, 2 * N, Epn, nbsP, Eall);
        {
            Job j0 = mkjob(offs_all, hs_pa, hs_pb, dinv_all, dinv_pos, b_init,
                           nullptr, nullptr, x_pos, W_pos);
            if (merged) { j0.W2 = W_neg; j0.dinv2 = dinv_neg; j0.hs_out2 = hs_nb; }
            const int g5 = max(nb64, (cntBpn + 3) / 4);
            stage0_fill<<<dim3(5 * g5), blk, 0, stream>>>(
                j0, p2, p3, offs3, rank, csr3, Eall, x_neg, N, nb64, cntBpn);
        }
    } else {
        // ---- fallback: monolithic count + cursor fill ----
        const int cntB = (Etot + TPB - 1) / TPB;
        {
            const int g5 = max((cntB + 2) / 3, (mmB + 1) / 2);
            count_mm<<<dim3(5 * g5), blk, 0, stream>>>(a0, a1, p2, p3, cnt3, nullptr,
                                                       H_t, W_init, x_pos, N, cntB, mmB);
        }
        const int nbs = (n3 + SCAN_T - 1) / SCAN_T;
        scan_block<<<nbs, SCAN_T, 0, stream>>>(cnt3, n3, offs3, bsums, dinv3);
        if (nbs <= 1024) {
            scan_add2<<<gblk(n3), blk, 0, stream>>>(offs3, bsums, n3, Etot, nbs, 0);
        } else {
            scan_sums<<<1, SCAN_T, 0, stream>>>(bsums, nbs);
            scan_add<<<gblk(n3), blk, 0, stream>>>(offs3, bsums, n3, Etot, 0);
        }
        scale_hs<<<gblk(N * 4), blk, 0, stream>>>(x_pos, dinv_all, hs_pa, N);
        FSeg f0 = { Apos_src, Apos_dst, E1, offs3, cur3 };
        FSeg f1 = { Aneg_src, Aneg_dst, E2, offs3, cur3 };
        FSeg f2 = { dApos_src, dApos_dst, DE1, offs3 + N, cur3 + N };
        FSeg f3 = { dAneg_src, dAneg_dst, DE2, offs3 + 2 * N, cur3 + 2 * N };
        fill4<<<gblk(Etot), blk, 0, stream>>>(f0, f1, f2, f3, csr3);
        {
            Job j0 = mkjob(offs_all, hs_pa, hs_pb, dinv_all, dinv_pos, b_init,
                           nullptr, nullptr, x_pos, W_pos);
            if (merged) { j0.W2 = W_neg; j0.dinv2 = dinv_neg; j0.hs_out2 = hs_nb; }
            stage0_fill<<<dim3(5 * nb64), blk, 0, stream>>>(
                j0, p2, p3, offs3, rank, csr3, Eall, x_neg, N, nb64, 0);
        }
    }

    if (merged) {
        for (int s = 0; s < 10; ++s) {
            float t0 = 0.1f * (float)s;
            Job p1j = mkjob(offs_pos, hs_pb, hs_pa, dinv_pos, dinv_pos, b_pos, wt_pos, ksum_p, x_pos, W_pos);
            Job n1j = mkjob(offs_neg, hs_nb, hs_na, dinv_neg, dinv_neg, b_neg, wt_neg, ksum_n, x_neg, W_neg);
            agg_stage<<<nsplit, blk, 0, stream>>>(p1j, n1j, nb64, t0, 1, 1, 1, N);
            Job p2j = p1j; p2j.hs_in = hs_pa; p2j.hs_out = hs_pb;
            Job n2j = n1j; n2j.hs_in = hs_na; n2j.hs_out = hs_nb;
            agg_stage<<<nsplit, blk, 0, stream>>>(p2j, n2j, nb64, t0 + 0.05f, 2, 1, 1, N);
            agg_stage<<<nsplit, blk, 0, stream>>>(p1j, n1j, nb64, t0 + 0.05f, 3, 1, 1, N);
            if (s < 9) {
                agg_stage<<<nsplit, blk, 0, stream>>>(p2j, n2j, nb64, t0 + 0.1f, 4, 1, 1, N);
            } else {
                stage4_combine<<<nb64, blk, 0, stream>>>(p2j, n2j, t0 + 0.1f,
                                                         W_comb, b_comb, ln_g, ln_b,
                                                         (float*)d_out, N);
            }
        }
    } else {
        for (int ode = 0; ode < 2; ++ode) {
            float* x = ode ? x_neg : x_pos;
            const float* W = ode ? W_neg : W_pos;
            const float* b = ode ? b_neg : b_pos;
            const float* wt = ode ? wt_neg : wt_pos;
            const float* dinv = ode ? dinv_neg : dinv_pos;
            const int* offs = ode ? offs_neg : offs_pos;
            if (ode == 1) {
                mm32_kernel<<<grid_rows, blk, 0, stream>>>(x, W, dinv, hs_pb, N);
            }
            for (int s = 0; s < 10; ++s) {
                float t0 = 0.1f * (float)s;
                int last_mm = (s == 9) ? 0 : 1;
                Job j1 = mkjob(offs, hs_pb, hs_pa, dinv, dinv, b, wt, ksum_p, x, W);
                Job j2 = j1; j2.hs_in = hs_pa; j2.hs_out = hs_pb;
                agg_stage<<<nb64, blk, 0, stream>>>(j1, j1, nb64, t0, 1, 1, 0, N);
                agg_stage<<<nb64, blk, 0, stream>>>(j2, j2, nb64, t0 + 0.05f, 2, 1, 0, N);
                agg_stage<<<nb64, blk, 0, stream>>>(j1, j1, nb64, t0 + 0.05f, 3, 1, 0, N);
                agg_stage<<<nb64, blk, 0, stream>>>(j2, j2, nb64, t0 + 0.1f, 4, last_mm, 0, N);
            }
        }
        combine_kernel<<<grid_rows, blk, 0, stream>>>(x_pos, x_neg, W_comb, b_comb, ln_g, ln_b,
                                                      (float*)d_out, N);
    }
}

// Round 6
// 1901.861 us; speedup vs baseline: 1.1133x; 1.1133x over previous
//
#include <hip/hip_runtime.h>
#include <math.h>

// DynamiSE: GCN + 2x RK4 neural ODE + combine/LN.
// R1: CSR gather, coef folded into matmul (hs = dinv * x@W).
// R2: mm32 fused into agg epilogue, hs double-buffered.
// R3: merged pos/neg dispatch.
// R4: fp16 hs (64B gather rows). FAILED replay (read-before-write of poison).
// R5: blanket memset(0) of used ws every call (determinism insurance).
// R6: radix CSR build REGRESSED (bucket windows thrash all 8 L2s) -> reverted.
// R7: persistent kernel REGRESSED (gather is fabric-fetch-bound) -> reverted.
// R9: XCD-split + fp16 ksum: small gain; gather fabric replication is structural.
// R10: rank-based atomic-free CSR fill (rank recorded in count pass).
// R11: XCD-local (workgroup-scope) atomics: NEUTRAL. ~23G op/s memory-side
//      atomic wall regardless of scope. count is a HW wall.
// R12: count+mm fusion (mm hidden under atomic wall); narrow memset; u16 rank.
// R13: f32-temp + fill-fused scale; stage0 dual-mm epilogue; stage4+combine/LN
//      fused; scan_sums absorbed. 2023->1954us.
// R14: pipelined CSR build: count ALL first (wall 200->141us), pn count hidden
//      under ALL-fill, pn fill hidden under stage0. 1954->1908us.
// R15: nt on ALL "single-use-per-dispatch" streams REGRESSED +209us. x/ksum/csr
//      are reused ACROSS dispatches; nt = no-allocate forced HBM refetch every
//      agg dispatch. LESSON: nt only for data dead after the kernel SEQUENCE.
//      Positive finding: nt on truly-dead build streams (edge lists, rank,
//      temp) cut count_mm_all 141->134.5us.
// R16: targeted revert. agg/stage0-gather/x/ksum/csr back to cached accesses;
//      keep nt only in build kernels (edges/rank/temp) + final out store.

#define TPB 256
#define SCAN_T 1024

typedef _Float16 h8 __attribute__((ext_vector_type(8)));
typedef float f8 __attribute__((ext_vector_type(8)));

template <typename T>
__device__ __forceinline__ T ntl(const T* p) { return __builtin_nontemporal_load(p); }
template <typename T>
__device__ __forceinline__ void nts(T* p, T v) { __builtin_nontemporal_store(v, p); }

// ---------- CSR build ----------

struct SegG { const int* src; const int* dst; int n; int goff; };
struct FSeg { const int* src; const int* dst; int n; const int* offs; int* cur; };

// count ALL graph (2 segs, goff=0) + mm128 (temp = H_t @ W_init, f32).
// nt on edge-list loads / rank stores / temp stores (dead after next reader).
__global__ __launch_bounds__(TPB) void count_mm_all(
        SegG s0, SegG s1, int* __restrict__ cnt3,
        unsigned short* __restrict__ rank,
        const float* __restrict__ x, const float* __restrict__ W,
        float* __restrict__ temp, int N, int cntB, int mmB) {
    __shared__ float Ws[128][32];
    __shared__ float xs[8][128];

    int g2 = blockIdx.x >> 1, r2 = blockIdx.x & 1;
    if (r2 == 0) {
        int cb = g2;
        if (cb >= cntB) return;
        int i = cb * TPB + threadIdx.x;
        SegG s; int e;
        if (i < s0.n) { s = s0; e = i; }
        else if (i < s0.n + s1.n) { s = s1; e = i - s0.n; }
        else return;
        int d = ntl(&s.dst[e]);
        int r = atomicAdd(&cnt3[d], 1);
        if (rank) nts(&rank[i], (unsigned short)r);
    } else {
        int mb = g2;
        if (mb >= mmB) return;
        int tid = threadIdx.x;
        for (int i = tid; i < 128 * 32; i += TPB) Ws[i >> 5][i & 31] = W[i];
        int base = mb * 8;
        for (int i = tid; i < 8 * 128; i += TPB) {
            int idx = base * 128 + i;
            xs[i >> 7][i & 127] = (idx < N * 128) ? ntl(&x[idx]) : 0.0f;
        }
        __syncthreads();
        int row = tid >> 5, c = tid & 31;
        int gr = base + row;
        float acc = 0.0f;
#pragma unroll
        for (int k = 0; k < 128; ++k) acc += xs[row][k] * Ws[k][c];
        if (gr < N) nts(&temp[gr * 32 + c], acc);
    }
}

// fallback: 4-seg count + mm (rank optional)
__global__ __launch_bounds__(TPB) void count_mm(
        SegG s0, SegG s1, SegG s2, SegG s3, int* __restrict__ cnt3,
        unsigned short* __restrict__ rank,
        const float* __restrict__ x, const float* __restrict__ W,
        float* __restrict__ temp, int N, int cntB, int mmB) {
    __shared__ float Ws[128][32];
    __shared__ float xs[8][128];

    int g5 = blockIdx.x / 5, r5 = blockIdx.x % 5;
    if (r5 < 3) {
        int cb = g5 * 3 + r5;
        if (cb >= cntB) return;
        int i = cb * TPB + threadIdx.x;
        SegG s; int e;
        if (i < s0.n) { s = s0; e = i; }
        else if (i < s0.n + s1.n) { s = s1; e = i - s0.n; }
        else if (i < s0.n + s1.n + s2.n) { s = s2; e = i - s0.n - s1.n; }
        else if (i < s0.n + s1.n + s2.n + s3.n) { s = s3; e = i - s0.n - s1.n - s2.n; }
        else return;
        int r = atomicAdd(&cnt3[s.goff + s.dst[e]], 1);
        if (rank) rank[i] = (unsigned short)r;
    } else {
        int mb = g5 * 2 + (r5 - 3);
        if (mb >= mmB) return;
        int tid = threadIdx.x;
        for (int i = tid; i < 128 * 32; i += TPB) Ws[i >> 5][i & 31] = W[i];
        int base = mb * 8;
        for (int i = tid; i < 8 * 128; i += TPB) {
            int idx = base * 128 + i;
            xs[i >> 7][i & 127] = (idx < N * 128) ? x[idx] : 0.0f;
        }
        __syncthreads();
        int row = tid >> 5, c = tid & 31;
        int gr = base + row;
        float acc = 0.0f;
#pragma unroll
        for (int k = 0; k < 128; ++k) acc += xs[row][k] * Ws[k][c];
        if (gr < N) temp[gr * 32 + c] = acc;
    }
}

// fill ALL csr + hs scale + count pos/neg, 8:1:4. nt on edges/rank/temp only;
// csr store stays CACHED (csr is read by all 40 gather dispatches).
__global__ __launch_bounds__(TPB) void fill_scale_count(
        SegG a0, SegG a1, SegG p2, SegG p3,
        const int* __restrict__ offs3, unsigned short* __restrict__ rank,
        int* __restrict__ csr,
        const float* __restrict__ temp, const float* __restrict__ dinv,
        _Float16* __restrict__ hs, int* __restrict__ cnt3,
        int N, int Eall, int fillB, int scaleB, int cntB) {
    int g = blockIdx.x / 13, r = blockIdx.x % 13;
    if (r < 8) {
        int fb = g * 8 + r;
        if (fb >= fillB) return;
        int i = fb * TPB + threadIdx.x;
        SegG s; int e;
        if (i < a0.n) { s = a0; e = i; }
        else if (i < a0.n + a1.n) { s = a1; e = i - a0.n; }
        else return;
        int d = ntl(&s.dst[e]);
        int sr = ntl(&s.src[e]);
        int rk = (int)ntl(&rank[i]);
        csr[offs3[d] + rk] = sr;
    } else if (r == 8) {
        int c = g * TPB + threadIdx.x;
        if (c < N * 4) {
            f8 v = ntl(&((const f8*)temp)[c]);
            ((h8*)hs)[c] = __builtin_convertvector(v * dinv[c >> 2], h8);
        }
    } else {
        int cb = g * 4 + (r - 9);
        if (cb >= cntB) return;
        int j = cb * TPB + threadIdx.x;
        SegG s; int e;
        if (j < p2.n) { s = p2; e = j; }
        else if (j < p2.n + p3.n) { s = p3; e = j - p2.n; }
        else return;
        int d = ntl(&s.dst[e]);
        int rr = atomicAdd(&cnt3[s.goff + d], 1);
        nts(&rank[Eall + j], (unsigned short)rr);
    }
}

// standalone scale (fallback path only)
__global__ void scale_hs(const float* __restrict__ temp, const float* __restrict__ dinv,
                         _Float16* __restrict__ hs, int N) {
    int c = blockIdx.x * blockDim.x + threadIdx.x;
    if (c < N * 4) {
        f8 v = ((const f8*)temp)[c];
        ((h8*)hs)[c] = __builtin_convertvector(v * dinv[c >> 2], h8);
    }
}

// fallback cursor fill (4 segs)
__global__ void fill4(FSeg s0, FSeg s1, FSeg s2, FSeg s3, int* __restrict__ csr) {
    int i = blockIdx.x * blockDim.x + threadIdx.x;
    FSeg s; int e;
    if (i < s0.n) { s = s0; e = i; }
    else if (i < s0.n + s1.n) { s = s1; e = i - s0.n; }
    else if (i < s0.n + s1.n + s2.n) { s = s2; e = i - s0.n - s1.n; }
    else if (i < s0.n + s1.n + s2.n + s3.n) { s = s3; e = i - s0.n - s1.n - s2.n; }
    else return;
    int d = s.dst[e];
    int pos = s.offs[d] + atomicAdd(&s.cur[d], 1);
    csr[pos] = s.src[e];
}

// scan over counts; also emits dinv
__global__ void scan_block(const int* __restrict__ in, int n, int* __restrict__ out,
                           int* __restrict__ bsums, float* __restrict__ dinv) {
    __shared__ int sh[SCAN_T];
    int tx = threadIdx.x;
    int g = blockIdx.x * SCAN_T + tx;
    int v = (g < n) ? in[g] : 0;
    if (g < n) dinv[g] = rsqrtf(1.0f + (float)v);
    sh[tx] = v;
    __syncthreads();
    for (int off = 1; off < SCAN_T; off <<= 1) {
        int t = (tx >= off) ? sh[tx - off] : 0;
        __syncthreads();
        sh[tx] += t;
        __syncthreads();
    }
    if (g < n) out[g] = sh[tx] - v;
    if (tx == SCAN_T - 1) bsums[blockIdx.x] = sh[tx];
}

__global__ void scan_sums(int* __restrict__ bsums, int nb) {
    __shared__ int sh[SCAN_T];
    int tx = threadIdx.x;
    int v = (tx < nb) ? bsums[tx] : 0;
    sh[tx] = v;
    __syncthreads();
    for (int off = 1; off < SCAN_T; off <<= 1) {
        int t = (tx >= off) ? sh[tx - off] : 0;
        __syncthreads();
        sh[tx] += t;
        __syncthreads();
    }
    if (tx < nb) bsums[tx] = sh[tx] - v;
}

__global__ void scan_add(int* __restrict__ offs, const int* __restrict__ bsums, int n,
                         int total, int base) {
    int g = blockIdx.x * blockDim.x + threadIdx.x;
    if (g < n) offs[g] += bsums[g >> 10] + base;
    if (g == 0) offs[n] = base + total;
}

// scan_add with scan_sums absorbed (raw bsums; LDS prefix). nbs <= 1024.
__global__ void scan_add2(int* __restrict__ offs, const int* __restrict__ bsums,
                          int n, int total, int nbs, int base) {
    __shared__ int sb[SCAN_T];
    int tid = threadIdx.x;
    for (int i = tid; i < nbs; i += TPB) sb[i] = bsums[i];
    __syncthreads();
    int g = blockIdx.x * TPB + tid;
    if (g < n) {
        int b = g >> 10;
        int pre = 0;
        for (int j = 0; j < b; ++j) pre += sb[j];
        offs[g] += pre + base;
    }
    if (g == 0) offs[n] = base + total;
}

// ---------- seed matmul (fallback path only) ----------

__global__ void mm32_kernel(const float* __restrict__ x, const float* __restrict__ W,
                            const float* __restrict__ dinv, _Float16* __restrict__ hs, int N) {
    __shared__ float Ws[32][32];
    __shared__ float xs[8][32];
    int tid = threadIdx.x;
    for (int i = tid; i < 32 * 32; i += TPB) Ws[i >> 5][i & 31] = W[i];
    int base = blockIdx.x * 8;
    {
        int idx = base * 32 + tid;
        xs[tid >> 5][tid & 31] = (idx < N * 32) ? x[idx] : 0.0f;
    }
    __syncthreads();
    int row = tid >> 5, c = tid & 31;
    int gr = base + row;
    float acc = 0.0f;
#pragma unroll
    for (int k = 0; k < 32; ++k) acc += xs[row][k] * Ws[k][c];
    if (gr < N) hs[gr * 32 + c] = (_Float16)(acc * dinv[gr]);
}

// ---------- fused CSR aggregate + RK4 stage + next matmul ----------

struct Job {
    const int* offs; const int* csr;
    const _Float16* hs_in; _Float16* hs_out;
    const float* dinv; const float* dinv_next;
    const float* bias; const float* wt;
    _Float16* ksum; float* x;
    const float* W;
    const float* W2; const float* dinv2; _Float16* hs_out2;  // stage0 only
};

// stage0 (all-graph gather + relu + dual mm epilogue) fused with pos/neg fill.
// Gather/x/csr paths CACHED (R16); only pn edges/rank loads are nt.
__global__ __launch_bounds__(TPB) void stage0_fill(
        Job J, SegG p2, SegG p3,
        const int* __restrict__ offs3, const unsigned short* __restrict__ rank,
        int* __restrict__ csr, int Eall,
        float* __restrict__ x2, int N, int nbg, int fillB) {
    __shared__ float Ws[32][32];
    __shared__ float Ws2[32][32];
    __shared__ float xts[64][36];
    __shared__ int soffs[65];

    int g = blockIdx.x / 5, r = blockIdx.x % 5;
    if (r != 0) {
        int fb = g * 4 + (r - 1);
        if (fb >= fillB) return;
        int j = fb * TPB + threadIdx.x;
        SegG s; int e;
        if (j < p2.n) { s = p2; e = j; }
        else if (j < p2.n + p3.n) { s = p3; e = j - p2.n; }
        else return;
        int d = ntl(&s.dst[e]);
        int sr = ntl(&s.src[e]);
        int rk = (int)ntl(&rank[Eall + j]);
        csr[offs3[s.goff + d] + rk] = sr;
        return;
    }
    int bid = g;
    if (bid >= nbg) return;

    int nbase = bid * 64;
    int tid = threadIdx.x;
    int lnode = tid >> 2, q = tid & 3;
    int node = nbase + lnode;
    bool valid = node < N;

    for (int i = tid; i < 32 * 32; i += TPB) Ws[i >> 5][i & 31] = J.W[i];
    if (J.W2) {
        for (int i = tid; i < 32 * 32; i += TPB) Ws2[i >> 5][i & 31] = J.W2[i];
    }
    if (tid < 65) {
        int ix = nbase + tid; if (ix > N) ix = N;
        soffs[tid] = J.offs[ix];
    }
    __syncthreads();

    f8 xrow;
#pragma unroll
    for (int j = 0; j < 8; ++j) xrow[j] = 0.f;

    if (valid) {
        const h8* hsv = (const h8*)J.hs_in;
        const int* __restrict__ csre = J.csr;
        int r0 = soffs[lnode], r1 = soffs[lnode + 1];
        f8 acc = __builtin_convertvector(hsv[node * 4 + q], f8); // self-loop
        int i = r0;
        for (; i + 4 <= r1; i += 4) {
            int e0 = csre[i], e1 = csre[i + 1], e2 = csre[i + 2], e3 = csre[i + 3];
            h8 v0 = hsv[e0 * 4 + q];
            h8 v1 = hsv[e1 * 4 + q];
            h8 v2 = hsv[e2 * 4 + q];
            h8 v3 = hsv[e3 * 4 + q];
            acc += (__builtin_convertvector(v0, f8) + __builtin_convertvector(v1, f8))
                 + (__builtin_convertvector(v2, f8) + __builtin_convertvector(v3, f8));
        }
        for (; i < r1; ++i)
            acc += __builtin_convertvector(hsv[csre[i] * 4 + q], f8);

        float dv = J.dinv[node];
        f8 bb = ((const f8*)J.bias)[q];
        f8 kv;
#pragma unroll
        for (int j = 0; j < 8; ++j) kv[j] = fmaxf(acc[j] * dv + bb[j], 0.f);
        int idx = node * 4 + q;
        ((f8*)J.x)[idx] = kv;
        ((f8*)x2)[idx] = kv;
        xrow = kv;
#pragma unroll
        for (int j = 0; j < 8; ++j) xts[lnode][q * 8 + j] = xrow[j];
    }
    __syncthreads();
    if (valid) {
        f8 accm;
#pragma unroll
        for (int j = 0; j < 8; ++j) accm[j] = 0.f;
#pragma unroll
        for (int k = 0; k < 32; ++k) {
            float xv = xts[lnode][k];
            f8 w = *(const f8*)&Ws[k][q * 8];
            accm += xv * w;
        }
        accm *= J.dinv_next[node];
        ((h8*)J.hs_out)[node * 4 + q] = __builtin_convertvector(accm, h8);
        if (J.W2) {
            f8 acc2;
#pragma unroll
            for (int j = 0; j < 8; ++j) acc2[j] = 0.f;
#pragma unroll
            for (int k = 0; k < 32; ++k) {
                float xv = xts[lnode][k];
                f8 w = *(const f8*)&Ws2[k][q * 8];
                acc2 += xv * w;
            }
            acc2 *= J.dinv2[node];
            ((h8*)J.hs_out2)[node * 4 + q] = __builtin_convertvector(acc2, h8);
        }
    }
}

// RK4 stages 1-4 (+ next matmul). 4 lanes/node, 64 nodes/block. All cached.
__global__ __launch_bounds__(TPB) void agg_stage(Job jp, Job jn, int nbg, float t,
                                                 int stage, int do_mm, int split, int N) {
    __shared__ float Ws[32][32];
    __shared__ float xts[64][36];
    __shared__ int soffs[65];

    bool isP; int bid;
    if (split) {
        int xcd = blockIdx.x & 7;
        isP = xcd < 4;
        bid = ((int)blockIdx.x >> 3) * 4 + (xcd & 3);
        if (bid >= nbg) return;
    } else {
        isP = (int)blockIdx.x < nbg;
        bid = isP ? blockIdx.x : (blockIdx.x - nbg);
    }
    const Job& J = isP ? jp : jn;
    int nbase = bid * 64;
    int tid = threadIdx.x;
    int lnode = tid >> 2, q = tid & 3;
    int node = nbase + lnode;
    bool valid = node < N;

    if (do_mm) {
        for (int i = tid; i < 32 * 32; i += TPB) Ws[i >> 5][i & 31] = J.W[i];
    }
    if (tid < 65) {
        int ix = nbase + tid; if (ix > N) ix = N;
        soffs[tid] = J.offs[ix];
    }
    __syncthreads();

    f8 xrow;
#pragma unroll
    for (int j = 0; j < 8; ++j) xrow[j] = 0.f;

    if (valid) {
        const h8* hsv = (const h8*)J.hs_in;
        const int* __restrict__ csr = J.csr;
        int r0 = soffs[lnode], r1 = soffs[lnode + 1];
        f8 acc = __builtin_convertvector(hsv[node * 4 + q], f8); // self-loop
        int i = r0;
        for (; i + 4 <= r1; i += 4) {
            int e0 = csr[i], e1 = csr[i + 1], e2 = csr[i + 2], e3 = csr[i + 3];
            h8 v0 = hsv[e0 * 4 + q];
            h8 v1 = hsv[e1 * 4 + q];
            h8 v2 = hsv[e2 * 4 + q];
            h8 v3 = hsv[e3 * 4 + q];
            acc += (__builtin_convertvector(v0, f8) + __builtin_convertvector(v1, f8))
                 + (__builtin_convertvector(v2, f8) + __builtin_convertvector(v3, f8));
        }
        for (; i < r1; ++i)
            acc += __builtin_convertvector(hsv[csr[i] * 4 + q], f8);

        float dv = J.dinv[node];
        f8 bb = ((const f8*)J.bias)[q];
        f8 kv;
#pragma unroll
        for (int j = 0; j < 8; ++j) kv[j] = fmaxf(acc[j] * dv + bb[j], 0.f);
        f8 w = ((const f8*)J.wt)[q];
#pragma unroll
        for (int j = 0; j < 8; ++j) kv[j] *= 1.f / (1.f + expf(-t * w[j]));

        int idx = node * 4 + q;
        f8* x8 = (f8*)J.x;
        h8* ks8 = (h8*)J.ksum;
        if (stage == 4) {
            f8 ks = __builtin_convertvector(ks8[idx], f8);
            f8 xv = x8[idx];
            const float cc = 0.1f / 6.0f;
#pragma unroll
            for (int j = 0; j < 8; ++j) xv[j] += cc * (ks[j] + kv[j]);
            x8[idx] = xv;
            xrow = xv;
        } else {
            float a = (stage == 3) ? 0.1f : 0.05f;
            f8 xv = x8[idx];
#pragma unroll
            for (int j = 0; j < 8; ++j) xrow[j] = xv[j] + a * kv[j];
            if (stage == 1) {
                ks8[idx] = __builtin_convertvector(kv, h8);
            } else {
                f8 ks = __builtin_convertvector(ks8[idx], f8);
#pragma unroll
                for (int j = 0; j < 8; ++j) ks[j] += 2.f * kv[j];
                ks8[idx] = __builtin_convertvector(ks, h8);
            }
        }
    }

    if (do_mm) {
        if (valid) {
#pragma unroll
            for (int j = 0; j < 8; ++j) xts[lnode][q * 8 + j] = xrow[j];
        }
        __syncthreads();
        if (valid) {
            f8 accm;
#pragma unroll
            for (int j = 0; j < 8; ++j) accm[j] = 0.f;
#pragma unroll
            for (int k = 0; k < 32; ++k) {
                float xv = xts[lnode][k];
                f8 w = *(const f8*)&Ws[k][q * 8];
                accm += xv * w;
            }
            accm *= J.dinv_next[node];
            ((h8*)J.hs_out)[node * 4 + q] = __builtin_convertvector(accm, h8);
        }
    }
}

// ---------- final RK4 stage fused with combine + layernorm ----------
__global__ __launch_bounds__(TPB) void stage4_combine(
        Job jp, Job jn, float t,
        const float* __restrict__ Wc, const float* __restrict__ bc,
        const float* __restrict__ lg, const float* __restrict__ lb,
        float* __restrict__ out, int N) {
    __shared__ float Ws[64][32];
    __shared__ float xts[64][68];
    __shared__ int soffs[65];

    int tid = threadIdx.x;
    for (int i = tid; i < 64 * 32; i += TPB) Ws[i >> 5][i & 31] = Wc[i];
    int nbase = blockIdx.x * 64;
    int lnode = tid >> 2, q = tid & 3;
    int node = nbase + lnode;
    bool valid = node < N;

    for (int side = 0; side < 2; ++side) {
        const Job& J = side ? jn : jp;
        __syncthreads();
        if (tid < 65) {
            int ix = nbase + tid; if (ix > N) ix = N;
            soffs[tid] = J.offs[ix];
        }
        __syncthreads();
        if (valid) {
            const h8* hsv = (const h8*)J.hs_in;
            const int* __restrict__ csr = J.csr;
            int r0 = soffs[lnode], r1 = soffs[lnode + 1];
            f8 acc = __builtin_convertvector(hsv[node * 4 + q], f8);
            int i = r0;
            for (; i + 4 <= r1; i += 4) {
                int e0 = csr[i], e1 = csr[i + 1], e2 = csr[i + 2], e3 = csr[i + 3];
                h8 v0 = hsv[e0 * 4 + q];
                h8 v1 = hsv[e1 * 4 + q];
                h8 v2 = hsv[e2 * 4 + q];
                h8 v3 = hsv[e3 * 4 + q];
                acc += (__builtin_convertvector(v0, f8) + __builtin_convertvector(v1, f8))
                     + (__builtin_convertvector(v2, f8) + __builtin_convertvector(v3, f8));
            }
            for (; i < r1; ++i)
                acc += __builtin_convertvector(hsv[csr[i] * 4 + q], f8);

            float dv = J.dinv[node];
            f8 bb = ((const f8*)J.bias)[q];
            f8 kv;
#pragma unroll
            for (int j = 0; j < 8; ++j) kv[j] = fmaxf(acc[j] * dv + bb[j], 0.f);
            f8 w = ((const f8*)J.wt)[q];
#pragma unroll
            for (int j = 0; j < 8; ++j) kv[j] *= 1.f / (1.f + expf(-t * w[j]));

            int idx = node * 4 + q;
            f8 ks = __builtin_convertvector(((const h8*)J.ksum)[idx], f8);
            f8 xv = ((const f8*)J.x)[idx];
            const float cc = 0.1f / 6.0f;
#pragma unroll
            for (int j = 0; j < 8; ++j)
                xts[lnode][side * 32 + q * 8 + j] = xv[j] + cc * (ks[j] + kv[j]);
        }
    }
    __syncthreads();

    if (valid) {
        f8 bcv = ((const f8*)bc)[q];
        f8 accm;
#pragma unroll
        for (int j = 0; j < 8; ++j) accm[j] = bcv[j];
#pragma unroll
        for (int k = 0; k < 64; ++k) {
            float xv = xts[lnode][k];
            f8 w = *(const f8*)&Ws[k][q * 8];
            accm += xv * w;
        }
        float s = 0.f, sq = 0.f;
#pragma unroll
        for (int j = 0; j < 8; ++j) { s += accm[j]; sq += accm[j] * accm[j]; }
        s += __shfl_xor(s, 1); s += __shfl_xor(s, 2);
        sq += __shfl_xor(sq, 1); sq += __shfl_xor(sq, 2);
        float mu = s * (1.0f / 32.0f);
        float var = sq * (1.0f / 32.0f) - mu * mu;
        float rs = rsqrtf(var + 1e-5f);
        f8 gv = ((const f8*)lg)[q];
        f8 bv = ((const f8*)lb)[q];
        f8 o;
#pragma unroll
        for (int j = 0; j < 8; ++j) o[j] = (accm[j] - mu) * rs * gv[j] + bv[j];
        nts(&((f8*)out)[node * 4 + q], o);  // d_out never re-read: nt safe
    }
}

// ---------- combine + layernorm (fallback path only) ----------

__global__ void combine_kernel(const float* __restrict__ zp, const float* __restrict__ zn,
                               const float* __restrict__ Wc, const float* __restrict__ bc,
                               const float* __restrict__ g, const float* __restrict__ be,
                               float* __restrict__ out, int N) {
    __shared__ float Ws[64][32];
    __shared__ float zs[8][64];
    int tid = threadIdx.x;
    for (int i = tid; i < 64 * 32; i += TPB) Ws[i >> 5][i & 31] = Wc[i];
    int base = blockIdx.x * 8;
    {
        int r = tid >> 5, c = tid & 31;
        int gr = base + r;
        zs[r][c] = (gr < N) ? zp[gr * 32 + c] : 0.0f;
        zs[r][32 + c] = (gr < N) ? zn[gr * 32 + c] : 0.0f;
    }
    __syncthreads();
    int row = tid >> 5, c = tid & 31;
    int gr = base + row;
    float acc = bc[c];
#pragma unroll
    for (int k = 0; k < 64; ++k) acc += zs[row][k] * Ws[k][c];
    float s = acc, sq = acc * acc;
#pragma unroll
    for (int off = 16; off; off >>= 1) {
        s += __shfl_xor(s, off, 32);
        sq += __shfl_xor(sq, off, 32);
    }
    float mu = s * (1.0f / 32.0f);
    float var = sq * (1.0f / 32.0f) - mu * mu;
    float y = (acc - mu) * rsqrtf(var + 1e-5f) * g[c] + be[c];
    if (gr < N) out[gr * 32 + c] = y;
}

// ---------- host orchestration ----------

extern "C" void kernel_launch(void* const* d_in, const int* in_sizes, int n_in,
                              void* d_out, int out_size, void* d_ws, size_t ws_size,
                              hipStream_t stream) {
    const float* H_t = (const float*)d_in[0];
    const int* Apos = (const int*)d_in[1];
    const int* Aneg = (const int*)d_in[2];
    const int* dApos = (const int*)d_in[3];
    const int* dAneg = (const int*)d_in[4];
    const float* W_init = (const float*)d_in[5];
    const float* b_init = (const float*)d_in[6];
    const float* W_pos = (const float*)d_in[7];
    const float* b_pos = (const float*)d_in[8];
    const float* wt_pos = (const float*)d_in[9];
    const float* W_neg = (const float*)d_in[10];
    const float* b_neg = (const float*)d_in[11];
    const float* wt_neg = (const float*)d_in[12];
    const float* W_comb = (const float*)d_in[13];
    const float* b_comb = (const float*)d_in[14];
    const float* ln_g = (const float*)d_in[15];
    const float* ln_b = (const float*)d_in[16];

    const int N = in_sizes[0] / 128;
    const int E1 = in_sizes[1] / 2;
    const int E2 = in_sizes[2] / 2;
    const int DE1 = in_sizes[3] / 2;
    const int DE2 = in_sizes[4] / 2;
    const int Eall = E1 + E2;
    const int Epn = DE1 + DE2;
    const int Etot = Eall + Epn;
    const int n3 = 3 * N;

    const int* Apos_src = Apos, * Apos_dst = Apos + E1;
    const int* Aneg_src = Aneg, * Aneg_dst = Aneg + E2;
    const int* dApos_src = dApos, * dApos_dst = dApos + DE1;
    const int* dAneg_src = dAneg, * dAneg_dst = dAneg + DE2;

    const size_t n32 = (size_t)N * 32;
    const size_t szf = n32 * 4;
    const size_t szh = n32 * 2;
    auto al = [](size_t b) { return (b + 255) & ~(size_t)255; };

    size_t small_bytes = 3 * al((size_t)n3 * 4)        /* dinv3, cnt3, cur3 */
                       + al(((size_t)n3 + 1) * 4)      /* offs3 */
                       + al((size_t)Etot * 4)          /* csr3 */
                       + al(SCAN_T * 4);
    size_t need_merged = 2 * al(szf) + 6 * al(szh) + small_bytes;
    size_t need_rank = need_merged + al((size_t)Etot * 2);   // u16 rank
    bool merged = ws_size >= need_merged + 4096;
    bool use_rank = ws_size >= need_rank + 4096;

    char* p = (char*)d_ws;
    auto alloc = [&](size_t bytes) -> void* {
        void* r = (void*)p;
        p += al(bytes);
        return r;
    };
    float* x_pos = (float*)alloc(szf);   // also: f32 temp for init mm (pre-stage0)
    float* x_neg = (float*)alloc(szf);
    _Float16* ksum_p = (_Float16*)alloc(szh);
    _Float16* ksum_n = merged ? (_Float16*)alloc(szh) : ksum_p;
    _Float16* hs_pa = (_Float16*)alloc(szh);
    _Float16* hs_pb = (_Float16*)alloc(szh);
    _Float16* hs_na = merged ? (_Float16*)alloc(szh) : hs_pa;
    _Float16* hs_nb = merged ? (_Float16*)alloc(szh) : hs_pb;
    float* dinv3 = (float*)alloc((size_t)n3 * 4);
    int* cnt3 = (int*)alloc((size_t)n3 * 4);
    int* cur3 = (int*)alloc((size_t)n3 * 4);
    int* offs3 = (int*)alloc(((size_t)n3 + 1) * 4);
    int* csr3 = (int*)alloc((size_t)Etot * 4);
    int* bsums = (int*)alloc(SCAN_T * 4);
    unsigned short* rank = use_rank ? (unsigned short*)alloc((size_t)Etot * 2) : nullptr;

    // Narrow memset: cnt3 always; cur3 only needed on the fallback cursor path.
    if (use_rank) {
        hipMemsetAsync(cnt3, 0, al((size_t)n3 * 4), stream);
    } else {
        hipMemsetAsync(cnt3, 0, 2 * al((size_t)n3 * 4), stream);
    }

    float* dinv_all = dinv3, * dinv_pos = dinv3 + N, * dinv_neg = dinv3 + 2 * N;
    const int* offs_all = offs3, * offs_pos = offs3 + N, * offs_neg = offs3 + 2 * N;

    dim3 blk(TPB);
    auto gblk = [](int n) { return dim3((n + TPB - 1) / TPB); };
    dim3 grid_rows((N + 7) / 8);
    const int nb64 = (N + 63) / 64;
    const int nsplit = ((nb64 + 3) / 4) * 8;
    const int mmB = (N + 7) / 8;
    const int scaleB = (N * 4 + TPB - 1) / TPB;

    SegG a0 = { Apos_src, Apos_dst, E1, 0 };
    SegG a1 = { Aneg_src, Aneg_dst, E2, 0 };
    SegG p2 = { dApos_src, dApos_dst, DE1, N };
    SegG p3 = { dAneg_src, dAneg_dst, DE2, 2 * N };

    auto mkjob = [&](const int* offs, const _Float16* hs_in, _Float16* hs_out,
                     const float* dinv, const float* dinv_next, const float* bias,
                     const float* wt, _Float16* ksum, float* x, const float* W) {
        Job j; j.offs = offs; j.csr = csr3; j.hs_in = hs_in; j.hs_out = hs_out;
        j.dinv = dinv; j.dinv_next = dinv_next; j.bias = bias; j.wt = wt;
        j.ksum = ksum; j.x = x; j.W = W;
        j.W2 = nullptr; j.dinv2 = nullptr; j.hs_out2 = nullptr; return j;
    };

    if (use_rank) {
        // ---- pipelined build ----
        const int cntBall = (Eall + TPB - 1) / TPB;
        count_mm_all<<<dim3(2 * max(cntBall, mmB)), blk, 0, stream>>>(
            a0, a1, cnt3, rank, H_t, W_init, x_pos, N, cntBall, mmB);
        const int nbsA = (N + SCAN_T - 1) / SCAN_T;
        scan_block<<<nbsA, SCAN_T, 0, stream>>>(cnt3, N, offs3, bsums, dinv3);
        scan_add2<<<gblk(N), blk, 0, stream>>>(offs3, bsums, N, Eall, nbsA, 0);
        const int cntBpn = (Epn + TPB - 1) / TPB;
        {
            const int g13 = max(max((cntBall + 7) / 8, scaleB), (cntBpn + 3) / 4);
            fill_scale_count<<<dim3(13 * g13), blk, 0, stream>>>(
                a0, a1, p2, p3, offs3, rank, csr3, x_pos, dinv_all, hs_pa,
                cnt3, N, Eall, cntBall, scaleB, cntBpn);
        }
        const int nbsP = (2 * N + SCAN_T - 1) / SCAN_T;
        scan_block<<<nbsP, SCAN_T, 0, stream>>>(cnt3 + N, 2 * N, offs3 + N, bsums, dinv3 + N);
        scan_add2<<<gblk(2 * N), blk, 0, stream>>>(offs3 + N, bsums, 2 * N, Epn, nbsP, Eall);
        {
            Job j0 = mkjob(offs_all, hs_pa, hs_pb, dinv_all, dinv_pos, b_init,
                           nullptr, nullptr, x_pos, W_pos);
            if (merged) { j0.W2 = W_neg; j0.dinv2 = dinv_neg; j0.hs_out2 = hs_nb; }
            const int g5 = max(nb64, (cntBpn + 3) / 4);
            stage0_fill<<<dim3(5 * g5), blk, 0, stream>>>(
                j0, p2, p3, offs3, rank, csr3, Eall, x_neg, N, nb64, cntBpn);
        }
    } else {
        // ---- fallback: monolithic count + cursor fill ----
        const int cntB = (Etot + TPB - 1) / TPB;
        {
            const int g5 = max((cntB + 2) / 3, (mmB + 1) / 2);
            count_mm<<<dim3(5 * g5), blk, 0, stream>>>(a0, a1, p2, p3, cnt3, nullptr,
                                                       H_t, W_init, x_pos, N, cntB, mmB);
        }
        const int nbs = (n3 + SCAN_T - 1) / SCAN_T;
        scan_block<<<nbs, SCAN_T, 0, stream>>>(cnt3, n3, offs3, bsums, dinv3);
        if (nbs <= 1024) {
            scan_add2<<<gblk(n3), blk, 0, stream>>>(offs3, bsums, n3, Etot, nbs, 0);
        } else {
            scan_sums<<<1, SCAN_T, 0, stream>>>(bsums, nbs);
            scan_add<<<gblk(n3), blk, 0, stream>>>(offs3, bsums, n3, Etot, 0);
        }
        scale_hs<<<gblk(N * 4), blk, 0, stream>>>(x_pos, dinv_all, hs_pa, N);
        FSeg f0 = { Apos_src, Apos_dst, E1, offs3, cur3 };
        FSeg f1 = { Aneg_src, Aneg_dst, E2, offs3, cur3 };
        FSeg f2 = { dApos_src, dApos_dst, DE1, offs3 + N, cur3 + N };
        FSeg f3 = { dAneg_src, dAneg_dst, DE2, offs3 + 2 * N, cur3 + 2 * N };
        fill4<<<gblk(Etot), blk, 0, stream>>>(f0, f1, f2, f3, csr3);
        {
            Job j0 = mkjob(offs_all, hs_pa, hs_pb, dinv_all, dinv_pos, b_init,
                           nullptr, nullptr, x_pos, W_pos);
            if (merged) { j0.W2 = W_neg; j0.dinv2 = dinv_neg; j0.hs_out2 = hs_nb; }
            stage0_fill<<<dim3(5 * nb64), blk, 0, stream>>>(
                j0, p2, p3, offs3, rank, csr3, Eall, x_neg, N, nb64, 0);
        }
    }

    if (merged) {
        for (int s = 0; s < 10; ++s) {
            float t0 = 0.1f * (float)s;
            Job p1j = mkjob(offs_pos, hs_pb, hs_pa, dinv_pos, dinv_pos, b_pos, wt_pos, ksum_p, x_pos, W_pos);
            Job n1j = mkjob(offs_neg, hs_nb, hs_na, dinv_neg, dinv_neg, b_neg, wt_neg, ksum_n, x_neg, W_neg);
            agg_stage<<<nsplit, blk, 0, stream>>>(p1j, n1j, nb64, t0, 1, 1, 1, N);
            Job p2j = p1j; p2j.hs_in = hs_pa; p2j.hs_out = hs_pb;
            Job n2j = n1j; n2j.hs_in = hs_na; n2j.hs_out = hs_nb;
            agg_stage<<<nsplit, blk, 0, stream>>>(p2j, n2j, nb64, t0 + 0.05f, 2, 1, 1, N);
            agg_stage<<<nsplit, blk, 0, stream>>>(p1j, n1j, nb64, t0 + 0.05f, 3, 1, 1, N);
            if (s < 9) {
                agg_stage<<<nsplit, blk, 0, stream>>>(p2j, n2j, nb64, t0 + 0.1f, 4, 1, 1, N);
            } else {
                stage4_combine<<<nb64, blk, 0, stream>>>(p2j, n2j, t0 + 0.1f,
                                                         W_comb, b_comb, ln_g, ln_b,
                                                         (float*)d_out, N);
            }
        }
    } else {
        for (int ode = 0; ode < 2; ++ode) {
            float* x = ode ? x_neg : x_pos;
            const float* W = ode ? W_neg : W_pos;
            const float* b = ode ? b_neg : b_pos;
            const float* wt = ode ? wt_neg : wt_pos;
            const float* dinv = ode ? dinv_neg : dinv_pos;
            const int* offs = ode ? offs_neg : offs_pos;
            if (ode == 1) {
                mm32_kernel<<<grid_rows, blk, 0, stream>>>(x, W, dinv, hs_pb, N);
            }
            for (int s = 0; s < 10; ++s) {
                float t0 = 0.1f * (float)s;
                int last_mm = (s == 9) ? 0 : 1;
                Job j1 = mkjob(offs, hs_pb, hs_pa, dinv, dinv, b, wt, ksum_p, x, W);
                Job j2 = j1; j2.hs_in = hs_pa; j2.hs_out = hs_pb;
                agg_stage<<<nb64, blk, 0, stream>>>(j1, j1, nb64, t0, 1, 1, 0, N);
                agg_stage<<<nb64, blk, 0, stream>>>(j2, j2, nb64, t0 + 0.05f, 2, 1, 0, N);
                agg_stage<<<nb64, blk, 0, stream>>>(j1, j1, nb64, t0 + 0.05f, 3, 1, 0, N);
                agg_stage<<<nb64, blk, 0, stream>>>(j2, j2, nb64, t0 + 0.1f, 4, last_mm, 0, N);
            }
        }
        combine_kernel<<<grid_rows, blk, 0, stream>>>(x_pos, x_neg, W_comb, b_comb, ln_g, ln_b,
                                                      (float*)d_out, N);
    }
}